// Round 4
// baseline (156.021 us; speedup 1.0000x reference)
//
#include <hip/hip_runtime.h>
#include <hip/hip_bf16.h>

#define HW  16384
#define WD  128
#define MNS (HW + 64)     // padded channel stride for mn workspace

#define TS   16           // output tile side
#define HS   18           // halo side (tile + 1 px border)
#define HP   (HS * HS)    // 324 halo pixels
#define VSTR 36           // LDS pixel stride in floats (mult of 4 -> b128 aligned)

// ---- k1: x -> mn (80 ch total), 1 px/thread ---------------------------------
__global__ __launch_bounds__(256) void la_k1(
    const float* __restrict__ x,
    const float* __restrict__ w1, const float* __restrict__ b1,
    const float* __restrict__ g1, const float* __restrict__ be1,
    const float* __restrict__ m1, const float* __restrict__ v1,
    const float* __restrict__ w2, const float* __restrict__ b2,
    const float* __restrict__ g2, const float* __restrict__ be2,
    const float* __restrict__ m2, const float* __restrict__ v2,
    float* __restrict__ mn)
{
    const int pix = blockIdx.x * blockDim.x + threadIdx.x;   // 0..16383
    const int bg  = blockIdx.y;
    const int b   = bg >> 3, g = bg & 7;

    const float* xp = x + (size_t)(b * 256 + g * 32) * HW + pix;
    float xg[32];
#pragma unroll
    for (int c = 0; c < 32; ++c) xg[c] = xp[(size_t)c * HW];

    // t = tanh(bn(gconv1(x)+b1))
    float t[8];
    const float* w1g = w1 + g * 256;
#pragma unroll
    for (int o = 0; o < 8; ++o) {
        float a = 0.f;
#pragma unroll
        for (int ci = 0; ci < 32; ++ci) a = fmaf(xg[ci], w1g[o * 32 + ci], a);
        const int ch = g * 8 + o;
        const float inv = g1[ch] * rsqrtf(v1[ch] + 1e-5f);
        const float add = be1[ch] + (b1[ch] - m1[ch]) * inv;
        t[o] = tanhf(fmaf(a, inv, add));
    }

    // mn = bn(gconv2(t)+b2), 10 channels
    const float* w2g = w2 + g * 80;
    float* mnp = mn + (size_t)(b * 80 + g * 10) * MNS + pix;
#pragma unroll
    for (int o = 0; o < 10; ++o) {
        float a = 0.f;
#pragma unroll
        for (int i = 0; i < 8; ++i) a = fmaf(t[i], w2g[o * 8 + i], a);
        const int ch = g * 10 + o;
        const float inv = g2[ch] * rsqrtf(v2[ch] + 1e-5f);
        const float add = be2[ch] + (b2[ch] - m2[ch]) * inv;
        mnp[(size_t)o * MNS] = fmaf(a, inv, add);
    }
}

// ---- k2: fused v-conv (LDS) + softmax attention + PV ------------------------
__global__ __launch_bounds__(256) void la_k2(
    const float* __restrict__ x, const float* __restrict__ wv,
    const float* __restrict__ mn, float* __restrict__ out)
{
    __shared__ __align__(16) float vt[HP * VSTR];   // 46656 B

    const int tid  = threadIdx.x;
    const int tile = blockIdx.x;              // 0..63
    const int bg   = blockIdx.y;
    const int b    = bg >> 3, g = bg & 7;
    const int ty0  = (tile >> 3) * TS;
    const int tx0  = (tile & 7) * TS;

    const float* xg  = x  + (size_t)(b * 256 + g * 32) * HW;
    const float* wvg = wv + g * 1024;

    // ---- phase 1: v = Wv*x on the 18x18 halo -> LDS (0 outside image) ----
    for (int hp = tid; hp < HP; hp += 256) {
        const int hy = hp / HS, hx = hp - hy * HS;
        const int iy = ty0 + hy - 1, ix = tx0 + hx - 1;
        float* dst = vt + hp * VSTR;
        if (((unsigned)iy < 128u) && ((unsigned)ix < 128u)) {
            const float* xp = xg + iy * WD + ix;
            float xv[32];
#pragma unroll
            for (int c = 0; c < 32; ++c) xv[c] = xp[(size_t)c * HW];
#pragma unroll
            for (int o4 = 0; o4 < 8; ++o4) {
                float a0 = 0.f, a1 = 0.f, a2 = 0.f, a3 = 0.f;
                const float* wp = wvg + o4 * 128;
#pragma unroll
                for (int c = 0; c < 32; ++c) {
                    const float xc = xv[c];
                    a0 = fmaf(xc, wp[c],      a0);
                    a1 = fmaf(xc, wp[32 + c], a1);
                    a2 = fmaf(xc, wp[64 + c], a2);
                    a3 = fmaf(xc, wp[96 + c], a3);
                }
                *(float4*)(dst + o4 * 4) = make_float4(a0, a1, a2, a3);
            }
        } else {
            const float4 z = make_float4(0.f, 0.f, 0.f, 0.f);
#pragma unroll
            for (int o4 = 0; o4 < 8; ++o4) *(float4*)(dst + o4 * 4) = z;
        }
    }
    __syncthreads();

    // ---- phase 2: logits + softmax + PV for one center pixel/thread ----
    const int cy  = tid >> 4, cx = tid & 15;
    const int iy  = ty0 + cy, ix = tx0 + cx;
    const int pix = iy * WD + ix;

    const float* nbp = mn + (size_t)(b * 80 + g) * MNS;
    const float* mkp = mn + (size_t)(b * 80 + 8 + g * 9) * MNS + pix;

    float lg[9];
    float mx = -1e30f;
#pragma unroll
    for (int k = 0; k < 9; ++k) {
        const int dy = k / 3 - 1, dx = k % 3 - 1;
        const int ny = iy + dy, nx = ix + dx;
        const bool ok = ((unsigned)ny < 128u) && ((unsigned)nx < 128u);
        const float nb = ok ? nbp[ny * WD + nx] : 0.f;
        lg[k] = mkp[(size_t)k * MNS] + nb;
        mx = fmaxf(mx, lg[k]);
    }
    float s = 0.f;
#pragma unroll
    for (int k = 0; k < 9; ++k) { lg[k] = __expf(lg[k] - mx); s += lg[k]; }
    const float rs = 1.f / s;
#pragma unroll
    for (int k = 0; k < 9; ++k) lg[k] *= rs;   // OOB taps hit v==0 in LDS

    // PV: 9 taps from LDS, 4 channels at a time
    float* og = out + (size_t)(b * 256 + g * 32) * HW + pix;
#pragma unroll 2
    for (int o4 = 0; o4 < 8; ++o4) {
        float a0 = 0.f, a1 = 0.f, a2 = 0.f, a3 = 0.f;
#pragma unroll
        for (int k = 0; k < 9; ++k) {
            const int hp = (cy + k / 3) * HS + (cx + k % 3);
            const float4 vv = *(const float4*)(vt + hp * VSTR + o4 * 4);
            a0 = fmaf(lg[k], vv.x, a0);
            a1 = fmaf(lg[k], vv.y, a1);
            a2 = fmaf(lg[k], vv.z, a2);
            a3 = fmaf(lg[k], vv.w, a3);
        }
        og[(size_t)(o4 * 4 + 0) * HW] = a0;
        og[(size_t)(o4 * 4 + 1) * HW] = a1;
        og[(size_t)(o4 * 4 + 2) * HW] = a2;
        og[(size_t)(o4 * 4 + 3) * HW] = a3;
    }
}

extern "C" void kernel_launch(void* const* d_in, const int* in_sizes, int n_in,
                              void* d_out, int out_size, void* d_ws, size_t ws_size,
                              hipStream_t stream)
{
    const float* x   = (const float*)d_in[0];
    const float* w1  = (const float*)d_in[1];
    const float* b1  = (const float*)d_in[2];
    const float* g1  = (const float*)d_in[3];
    const float* be1 = (const float*)d_in[4];
    const float* m1  = (const float*)d_in[5];
    const float* v1  = (const float*)d_in[6];
    const float* w2  = (const float*)d_in[7];
    const float* b2  = (const float*)d_in[8];
    const float* g2  = (const float*)d_in[9];
    const float* be2 = (const float*)d_in[10];
    const float* m2  = (const float*)d_in[11];
    const float* v2  = (const float*)d_in[12];
    const float* wv  = (const float*)d_in[13];

    float* out = (float*)d_out;
    float* mn  = (float*)d_ws;     // 2*80*MNS floats = 42.1 MB

    dim3 blk(256);
    dim3 g1d(HW / 256, 16);        // 1 px/thread -> 1024 blocks
    dim3 g2d(64, 16);              // 64 tiles x 16 (b,g) -> 1024 blocks

    hipLaunchKernelGGL(la_k1, g1d, blk, 0, stream,
                       x, w1, b1, g1, be1, m1, v1, w2, b2, g2, be2, m2, v2, mn);
    hipLaunchKernelGGL(la_k2, g2d, blk, 0, stream, x, wv, mn, out);
}